// Round 1
// 838.603 us; speedup vs baseline: 1.1058x; 1.1058x over previous
//
#include <hip/hip_runtime.h>

#define NB 64
#define NC 32
#define NH 16
#define NW 16
#define NE 4096
#define NTOT (NB*NC*NH*NW)   // 524288
#define IDXW 341             // 1+4+16+64+256
#define GRID 256
#define TPB 1024
#define NBAR 16

__device__ __forceinline__ double cubicw(double x) {
  const double A = -0.75;
  x = fabs(x);
  if (x <= 1.0) return ((A + 2.0) * x - (A + 3.0)) * x * x + 1.0;
  if (x < 2.0)  return A * (((x - 5.0) * x + 8.0) * x - 4.0);
  return 0.0;
}

// One-shot software grid barrier (one counter per barrier, never reused).
// GRID=256 = #CUs: all blocks co-resident.
// v2: poll with relaxed atomic LOAD (no RMW ownership ping-pong) + longer sleep.
__device__ __forceinline__ void gridbar(unsigned* bar) {
  __syncthreads();
  if (threadIdx.x == 0) {
    __threadfence();                       // release (flush dirty L2 to coherent point)
    atomicAdd(bar, 1u);                    // single arrive RMW per block
    while (__hip_atomic_load(bar, __ATOMIC_RELAXED, __HIP_MEMORY_SCOPE_AGENT)
           < (unsigned)GRID)
      __builtin_amdgcn_s_sleep(8);         // ~512 clk between read-only polls
    __threadfence();                       // acquire (invalidate stale cached lines)
  }
  __syncthreads();
}

__global__ __launch_bounds__(TPB, 4) void k_fused(
    const float* __restrict__ z, const float* __restrict__ emb,
    const float* __restrict__ phi_w, const float* __restrict__ phi_b,
    double* __restrict__ z_res, double* __restrict__ emb_sq,
    double* __restrict__ lossArr,
    float* __restrict__ emb_t, int* __restrict__ idx_ws,
    unsigned* __restrict__ bars,
    float* __restrict__ out_zhat, float* __restrict__ out_loss,
    float* __restrict__ out_idx)
{
  __shared__ double lds[8192];   // 64 KB scratch, reused per phase
  const int tid = threadIdx.x;
  const int bid = blockIdx.x;

  // Poisoned (0xAA) barrier counters: idempotent CAS-init by every block.
  if (tid < NBAR) atomicCAS(&bars[tid], 0xAAAAAAAAu, 0u);
  __syncthreads();
  int bar_i = 0;
  double bloss = 0.0;            // per-block loss partial (tid 0 meaningful)

  // ---------- setup: z_res init + emb transpose + emb_sq ----------
  for (int i = bid * TPB + tid; i < NTOT; i += GRID * TPB)
    z_res[i] = (double)z[i];
  if (bid < 64) {
    float* tile = (float*)lds;            // [64][33]
    int e0 = bid * 64;
    for (int t = tid; t < 2048; t += TPB) {
      int el = t >> 5, c = t & 31;
      tile[el * 33 + c] = emb[(e0 + el) * NC + c];
    }
    __syncthreads();
    for (int t = tid; t < 2048; t += TPB) {
      int c = t >> 6, ep = t & 63;
      emb_t[c * NE + e0 + ep] = tile[ep * 33 + c];
    }
    if (tid < 64) {
      const float* tr = &tile[tid * 33];
      double s = 0.0;
      #pragma unroll
      for (int j = 0; j < 8; j++)
        s += (double)tr[4*j]*tr[4*j] + (double)tr[4*j+1]*tr[4*j+1]
           + (double)tr[4*j+2]*tr[4*j+2] + (double)tr[4*j+3]*tr[4*j+3];
      emb_sq[e0 + tid] = s;
    }
  }
  gridbar(&bars[bar_i++]);

  const int phs[5]  = {1, 2, 4, 8, 16};
  // ticks = np.linspace(1/12, 11/12, 4) f64: si=2 tie breaks to pi=2
  // via 2-ulp linspace rounding (verified by exact mantissa calc).
  const int pis[5]  = {0, 1, 2, 2, 3};
  const int offs[5] = {0, 1, 5, 21, 85};

  for (int si = 0; si < 5; si++) {
    const int ph = phs[si], f = NH / ph;
    const int idx_off = offs[si];

    // ---------- argmin (fused area-pool, fp64 distances) ----------
    {
      double* rv = lds;                   // [8][32]
      double* pp = rv + 256;              // [256][4] pool partials
      double* wd = pp + 1024;             // [16][8]
      int*    wi = (int*)(wd + 128);      // [16][8]
      int nchunks = (NB * ph * ph) >> 3;  // rows / 8  (always exact: 64*ph^2 % 8 == 0)
      for (int chunk = bid; chunk < nchunks; chunk += GRID) {
        int row0 = chunk * 8;
        // pool: 256 bins x up-to-4 dy-partials => 4 independent load chains/bin
        {
          int bin = tid & 255, part = tid >> 8;
          int j = bin >> 5, c = bin & 31;
          int n = row0 + j;
          int x = n % ph, y = (n / ph) % ph, b = n / (ph * ph);
          const double* base = z_res + (((b * NC + c) * NH) + y * f) * NW + x * f;
          int P = (f >= 4) ? 4 : f;
          if (part < P) {
            int dpp = f / P;
            int d0 = part * dpp, d1 = d0 + dpp;
            double s = 0.0;
            for (int dy = d0; dy < d1; dy++) {
              const double* rp = base + dy * NW;
              #pragma unroll 4
              for (int dx = 0; dx < f; dx++) s += rp[dx];
            }
            pp[bin * 4 + part] = s;
          }
          __syncthreads();
          if (tid < 256) {
            double t = pp[tid * 4];
            for (int p2 = 1; p2 < P; p2++) t += pp[tid * 4 + p2];
            rv[j * NC + c] = t / (double)(f * f);
          }
        }
        __syncthreads();
        double best[8]; int bidx[8];
        #pragma unroll
        for (int j = 0; j < 8; j++) { best[j] = 1e300; bidx[j] = 0; }
        #pragma unroll
        for (int pass = 0; pass < 2; pass++) {   // 1024 threads x 2 entries x 2 passes
          int e0 = pass * 2048 + tid * 2;
          double acc[8][2];
          #pragma unroll
          for (int j = 0; j < 8; j++) { acc[j][0] = 0.0; acc[j][1] = 0.0; }
          #pragma unroll 4
          for (int k = 0; k < NC; k++) {
            float2 e2 = *(const float2*)(emb_t + k * NE + e0);  // coalesced 8B/lane
            double d0 = e2.x, d1 = e2.y;
            #pragma unroll
            for (int j = 0; j < 8; j++) {
              double rj = rv[j * NC + k];
              acc[j][0] += rj * d0; acc[j][1] += rj * d1;
            }
          }
          #pragma unroll
          for (int v = 0; v < 2; v++) {      // ascending e per thread
            double esq = emb_sq[e0 + v];
            #pragma unroll
            for (int j = 0; j < 8; j++) {
              double d = esq - 2.0 * acc[j][v];
              if (d < best[j]) { best[j] = d; bidx[j] = e0 + v; }
            }
          }
        }
        #pragma unroll
        for (int j = 0; j < 8; j++) {
          double d = best[j]; int bi2 = bidx[j];
          #pragma unroll
          for (int off = 32; off >= 1; off >>= 1) {
            double od = __shfl_xor(d, off, 64);
            int oi = __shfl_xor(bi2, off, 64);
            if (od < d || (od == d && oi < bi2)) { d = od; bi2 = oi; }
          }
          best[j] = d; bidx[j] = bi2;
        }
        int wave = tid >> 6, lane = tid & 63;
        if (lane == 0) {
          #pragma unroll
          for (int j = 0; j < 8; j++) { wd[wave * 8 + j] = best[j]; wi[wave * 8 + j] = bidx[j]; }
        }
        __syncthreads();
        if (tid < 8) {
          double d = wd[tid]; int bi2 = wi[tid];
          #pragma unroll
          for (int w2 = 1; w2 < 16; w2++) {
            double od = wd[w2 * 8 + tid]; int oi = wi[w2 * 8 + tid];
            if (od < d || (od == d && oi < bi2)) { d = od; bi2 = oi; }
          }
          int n = row0 + tid;
          idx_ws[n] = bi2;
          int x = n % ph, y = (n / ph) % ph, b = n / (ph * ph);
          out_idx[b * IDXW + idx_off + y * ph + x] = (float)bi2;
        }
        __syncthreads();   // LDS reused next chunk iteration
      }
    }
    gridbar(&bars[bar_i++]);

    // ---------- fused upsample + phi (each block builds full 32-ch q in LDS) ----
    {
      int b = bid >> 2, co0 = (bid & 3) * 8;
      float* simg = (float*)lds;                     // [32][256] f32, bytes [0,32768)
      const int ph2 = ph * ph;
      if (ph == 16) {
        for (int i = tid; i < 32 * 256; i += TPB) {
          int j = i >> 8, pix = i & 255;
          simg[i] = emb[idx_ws[b * 256 + pix] * NC + j];
        }
      } else {
        float* qs  = (float*)((char*)lds + 24576);   // [32][ph2] f32 <= 8KB (dead before simg write)
        double* tt = (double*)((char*)lds + 32768);  // [32][16][ph] f64 <= 32KB
        for (int i = tid; i < 32 * ph2; i += TPB) {
          int j = i / ph2, rem = i % ph2;
          qs[i] = emb[idx_ws[b * ph2 + rem] * NC + j];
        }
        __syncthreads();
        double scale = (double)ph / 16.0;
        for (int i = tid; i < 32 * 16 * ph; i += TPB) {   // H pass (y)
          int x = i % ph; int oy = (i / ph) % 16; int j = i / (16 * ph);
          double src = ((double)oy + 0.5) * scale - 0.5;
          double fi = floor(src);
          int i0 = (int)fi;
          double frac = src - fi;
          double s = 0.0;
          #pragma unroll
          for (int k = 0; k < 4; k++) {
            int iy = min(max(i0 + k - 1, 0), ph - 1);
            s += cubicw(frac - (double)(k - 1)) * (double)qs[(j * ph + iy) * ph + x];
          }
          tt[i] = s;
        }
        __syncthreads();
        for (int i = tid; i < 32 * 256; i += TPB) {       // W pass (x) -> simg f32
          int ox = i & 15; int oy = (i >> 4) & 15; int j = i >> 8;
          double src = ((double)ox + 0.5) * scale - 0.5;
          double fi = floor(src);
          int i0 = (int)fi;
          double frac = src - fi;
          double s = 0.0;
          #pragma unroll
          for (int k = 0; k < 4; k++) {
            int ix = min(max(i0 + k - 1, 0), ph - 1);
            s += cubicw(frac - (double)(k - 1)) * tt[(j * 16 + oy) * ph + ix];
          }
          simg[i] = (float)s;
        }
      }
      __syncthreads();

      // phi: 0.5*x + 0.5*(conv3x3(x)+b), residual + loss
      int pix = tid & 255, sub = tid >> 8;   // 4 subs x 2 co = 8 co per block
      int x = pix & 15, y = pix >> 4;
      double acc[2] = {0.0, 0.0};
      const float* w = phi_w + pis[si] * NC * NC * 9;
      for (int ci = 0; ci < NC; ci++) {
        double wv[9];
        #pragma unroll
        for (int ky = 0; ky < 3; ky++) {
          int yy = y + ky - 1;
          #pragma unroll
          for (int kx = 0; kx < 3; kx++) {
            int xx = x + kx - 1;
            wv[ky * 3 + kx] = (yy >= 0 && yy < NH && xx >= 0 && xx < NW)
                              ? (double)simg[ci * 256 + yy * 16 + xx] : 0.0;
          }
        }
        #pragma unroll
        for (int j = 0; j < 2; j++) {
          const float* wp = w + ((co0 + sub * 2 + j) * NC + ci) * 9;  // wave-uniform
          double a = acc[j];
          #pragma unroll
          for (int k = 0; k < 9; k++) a += wv[k] * (double)wp[k];
          acc[j] = a;
        }
      }
      double lsum = 0.0;
      #pragma unroll
      for (int j = 0; j < 2; j++) {
        int co = co0 + sub * 2 + j;
        int i = co * 256 + pix;
        int gi = b * NC * 256 + i;
        double val = (double)simg[i] * 0.5 + (acc[j] + (double)(phi_b[pis[si] * NC + co])) * 0.5;
        double zr = z_res[gi] - val;
        z_res[gi] = zr;
        if (si == 4) out_zhat[gi] = (float)((double)z[gi] - zr);
        lsum += zr * zr;   // z_hat - z == -z_res
      }
      __syncthreads();               // simg contents consumed
      double* red = lds;             // reuse LDS for reduction
      red[tid] = lsum; __syncthreads();
      for (int s = 512; s > 0; s >>= 1) {
        if (tid < s) red[tid] += red[tid + s];
        __syncthreads();
      }
      if (tid == 0) {
        bloss += red[0];
        if (si == 4) lossArr[bid] = bloss;   // before final bar => covered by release
      }
    }
    gridbar(&bars[bar_i++]);
  }

  // ---------- final loss reduction (block 0 only, post-acquire) ----------
  if (bid == 0) {
    double v = (tid < GRID) ? lossArr[tid] : 0.0;
    double* red = lds;
    red[tid] = v; __syncthreads();
    for (int s = 512; s > 0; s >>= 1) {
      if (tid < s) red[tid] += red[tid + s];
      __syncthreads();
    }
    if (tid == 0) *out_loss = (float)(red[0] * (1.25 / (5.0 * (double)NTOT)));
  }
}

extern "C" void kernel_launch(void* const* d_in, const int* in_sizes, int n_in,
                              void* d_out, int out_size, void* d_ws, size_t ws_size,
                              hipStream_t stream) {
  const float* z     = (const float*)d_in[0];   // [64,32,16,16]
  const float* emb   = (const float*)d_in[1];   // [4096,32]
  const float* phi_w = (const float*)d_in[2];   // [4,32,32,3,3]
  const float* phi_b = (const float*)d_in[3];   // [4,32]

  float* out      = (float*)d_out;
  float* out_zhat = out;
  float* out_loss = out + NTOT;
  float* out_idx  = out + NTOT + 1; // [64,341] as floats

  double* ws      = (double*)d_ws;
  double* z_res   = ws;                       // 524288 f64
  double* emb_sq  = z_res + NTOT;             // 4096 f64
  double* lossArr = emb_sq + NE;              // 256 f64 per-block partials
  float* emb_t    = (float*)(lossArr + GRID); // 131072 f32
  int* idx_ws     = (int*)(emb_t + NE * NC);  // 16384 int
  unsigned* bars  = (unsigned*)(idx_ws + NB * 256);  // 16 one-shot barrier counters

  k_fused<<<GRID, TPB, 0, stream>>>(z, emb, phi_w, phi_b,
                                    z_res, emb_sq, lossArr,
                                    emb_t, idx_ws, bars,
                                    out_zhat, out_loss, out_idx);
}